// Round 2
// baseline (704.944 us; speedup 1.0000x reference)
//
#include <hip/hip_runtime.h>
#include <hip/hip_bf16.h>
#include <math.h>

// B=4 S=2048 D=1024 H=16 DK=DV=64 DI=4096.
// I/O: float tensors are fp32 (per reference), mask int32, output fp32.
// Internal: bf16 operands for MFMA, fp32 accumulation; `attn` residual fp32.

typedef __attribute__((ext_vector_type(8))) short bf16x8;  // 8 bf16 = 4 VGPR
typedef __attribute__((ext_vector_type(4))) short bf16x4;
typedef __attribute__((ext_vector_type(4))) float f32x4;

__device__ __forceinline__ float bs2f(short s) {
  union { unsigned u; float f; } c; c.u = ((unsigned)(unsigned short)s) << 16; return c.f;
}
__device__ __forceinline__ short f2bs(float x) {
  union { float f; unsigned u; } c; c.f = x;
  unsigned r = c.u + 0x7FFFu + ((c.u >> 16) & 1u);   // RNE
  return (short)(r >> 16);
}

// ------ transpose+convert: in[R][C] fp32 -> out[C][R] bf16, batched ---------
__global__ __launch_bounds__(256) void k_transpose(const float* __restrict__ in,
                                                   short* __restrict__ out, int R, int C) {
  __shared__ float t[32][33];
  const long bat = blockIdx.z;
  const float* ib = in + bat * (long)R * C;
  short* ob = out + bat * (long)R * C;
  int tx = threadIdx.x & 31, ty = threadIdx.x >> 5;
  int r0 = blockIdx.y * 32, c0 = blockIdx.x * 32;
#pragma unroll
  for (int i = 0; i < 32; i += 8) t[ty + i][tx] = ib[(long)(r0 + ty + i) * C + c0 + tx];
  __syncthreads();
#pragma unroll
  for (int i = 0; i < 32; i += 8) ob[(long)(c0 + ty + i) * R + r0 + tx] = f2bs(t[tx][ty + i]);
}

// -------- mask pack: mask[b][s][t] int32 -> bits mbt[b][t/64][s] (u64) ------
__global__ __launch_bounds__(256) void k_packmask(const int* __restrict__ mask,
                                                  unsigned long long* __restrict__ mbt) {
  long gw = (long)blockIdx.x * 4 + (threadIdx.x >> 6);  // (b*2048+s)*32 + w
  int lane = threadIdx.x & 63;
  long bs = gw >> 5; int w = (int)(gw & 31);
  int b = (int)(bs >> 11), s = (int)(bs & 2047);
  int mval = mask[bs * 2048 + w * 64 + lane];
  unsigned long long bits = __ballot(mval != 0);
  if (lane == 0) mbt[((long)b * 32 + w) * 2048 + s] = bits;
}

// ------------- layernorm: X fp32 row(1024) -> Y bf16 ------------------------
__global__ __launch_bounds__(256) void k_ln(const float* __restrict__ X,
    const float* __restrict__ G, const float* __restrict__ Bb, short* __restrict__ Y) {
  __shared__ float ps[8];
  long row = blockIdx.x;
  int tid = threadIdx.x, wid = tid >> 6;
  f32x4 f = *(const f32x4*)(X + row * 1024 + tid * 4);
  float s = f[0] + f[1] + f[2] + f[3];
  float qq = f[0]*f[0] + f[1]*f[1] + f[2]*f[2] + f[3]*f[3];
#pragma unroll
  for (int o = 32; o; o >>= 1) { s += __shfl_xor(s, o); qq += __shfl_xor(qq, o); }
  if ((tid & 63) == 0) { ps[wid] = s; ps[4 + wid] = qq; }
  __syncthreads();
  s = ps[0] + ps[1] + ps[2] + ps[3];
  qq = ps[4] + ps[5] + ps[6] + ps[7];
  float mu = s * (1.f / 1024.f);
  float rstd = rsqrtf(qq * (1.f / 1024.f) - mu * mu + 1e-5f);
  f32x4 gv = *(const f32x4*)(G + tid * 4);
  f32x4 bv = *(const f32x4*)(Bb + tid * 4);
  bf16x4 yv;
#pragma unroll
  for (int i = 0; i < 4; i++) yv[i] = f2bs((f[i] - mu) * rstd * gv[i] + bv[i]);
  *(bf16x4*)(Y + row * 1024 + tid * 4) = yv;
}

// ------- double layernorm: X fp32 -> LN(LN(x;g1,b1);g2,b2) -> Y bf16 --------
__global__ __launch_bounds__(256) void k_ln2(const float* __restrict__ X,
    const float* __restrict__ G1, const float* __restrict__ B1,
    const float* __restrict__ G2, const float* __restrict__ B2, short* __restrict__ Y) {
  __shared__ float ps[8];
  long row = blockIdx.x;
  int tid = threadIdx.x, wid = tid >> 6;
  f32x4 f = *(const f32x4*)(X + row * 1024 + tid * 4);
  float s = f[0] + f[1] + f[2] + f[3];
  float qq = f[0]*f[0] + f[1]*f[1] + f[2]*f[2] + f[3]*f[3];
#pragma unroll
  for (int o = 32; o; o >>= 1) { s += __shfl_xor(s, o); qq += __shfl_xor(qq, o); }
  if ((tid & 63) == 0) { ps[wid] = s; ps[4 + wid] = qq; }
  __syncthreads();
  s = ps[0] + ps[1] + ps[2] + ps[3];
  qq = ps[4] + ps[5] + ps[6] + ps[7];
  float mu = s * (1.f / 1024.f);
  float rstd = rsqrtf(qq * (1.f / 1024.f) - mu * mu + 1e-5f);
  f32x4 g1 = *(const f32x4*)(G1 + tid * 4);
  f32x4 b1 = *(const f32x4*)(B1 + tid * 4);
  float y[4];
#pragma unroll
  for (int i = 0; i < 4; i++) y[i] = (f[i] - mu) * rstd * g1[i] + b1[i];
  __syncthreads();  // everyone done reading ps
  float s2 = y[0] + y[1] + y[2] + y[3];
  float q2 = y[0]*y[0] + y[1]*y[1] + y[2]*y[2] + y[3]*y[3];
#pragma unroll
  for (int o = 32; o; o >>= 1) { s2 += __shfl_xor(s2, o); q2 += __shfl_xor(q2, o); }
  if ((tid & 63) == 0) { ps[wid] = s2; ps[4 + wid] = q2; }
  __syncthreads();
  s2 = ps[0] + ps[1] + ps[2] + ps[3];
  q2 = ps[4] + ps[5] + ps[6] + ps[7];
  float mu2 = s2 * (1.f / 1024.f);
  float rstd2 = rsqrtf(q2 * (1.f / 1024.f) - mu2 * mu2 + 1e-5f);
  f32x4 g2 = *(const f32x4*)(G2 + tid * 4);
  f32x4 b2 = *(const f32x4*)(B2 + tid * 4);
  bf16x4 yv;
#pragma unroll
  for (int i = 0; i < 4; i++) yv[i] = f2bs((y[i] - mu2) * rstd2 * g2[i] + b2[i]);
  *(bf16x4*)(Y + row * 1024 + tid * 4) = yv;
}

// ---------------- GEMM: C[M,N] = A[M,K] * Bt[N,K]^T, bf16 operands ----------
// EPI: 0 = scale+store bf16 [B,H,S,DK] (q/k)   1 = store bf16 V^T [B,H,DV,S]
//      2 = +X1(fp32) residual -> fp32 row-major
//      3 = +bias X1(fp32), gelu -> bf16 row-major
//      4 = +bias X1(fp32) + X2(fp32) residual -> fp32 row-major
template<int EPI>
__global__ __launch_bounds__(256, 2) void k_gemm(
    const short* __restrict__ A, const short* __restrict__ Bt, void* __restrict__ Cv,
    const float* __restrict__ X1, const float* __restrict__ X2,
    int M, int N, int K, float scale) {
  __shared__ short As[128 * 32];
  __shared__ short Bs[128 * 32];
  const int tid = threadIdx.x;
  const int wid = tid >> 6, lane = tid & 63;
  const int ntn = N >> 7;
  const int tm = blockIdx.x / ntn, tn = blockIdx.x % ntn;
  const long m0 = (long)tm << 7, n0 = (long)tn << 7;
  const int wm = (wid >> 1) << 6, wn = (wid & 1) << 6;
  const int l15 = lane & 15, l4 = lane >> 4;

  f32x4 acc[4][4] = {};

  const short* Ag = A + (m0 + (tid >> 2)) * (long)K + (tid & 3) * 8;
  const short* Bg = Bt + (n0 + (tid >> 2)) * (long)K + (tid & 3) * 8;

  for (int kk = 0; kk < K; kk += 32) {
#pragma unroll
    for (int i = 0; i < 2; i++) {
      __builtin_amdgcn_global_load_lds(
          (const __attribute__((address_space(1))) unsigned int*)(Ag + kk + (long)i * 64 * K),
          (__attribute__((address_space(3))) unsigned int*)((char*)As + wid * 1024 + i * 4096),
          16, 0, 0);
      __builtin_amdgcn_global_load_lds(
          (const __attribute__((address_space(1))) unsigned int*)(Bg + kk + (long)i * 64 * K),
          (__attribute__((address_space(3))) unsigned int*)((char*)Bs + wid * 1024 + i * 4096),
          16, 0, 0);
    }
    __syncthreads();
    const int kof = l4 * 8;
    bf16x8 a[4], bfr[4];
#pragma unroll
    for (int i = 0; i < 4; i++) a[i] = *(const bf16x8*)(As + (wm + i * 16 + l15) * 32 + kof);
#pragma unroll
    for (int j = 0; j < 4; j++) bfr[j] = *(const bf16x8*)(Bs + (wn + j * 16 + l15) * 32 + kof);
#pragma unroll
    for (int i = 0; i < 4; i++)
#pragma unroll
      for (int j = 0; j < 4; j++)
        acc[i][j] = __builtin_amdgcn_mfma_f32_16x16x32_bf16(a[i], bfr[j], acc[i][j], 0, 0, 0);
    __syncthreads();
  }

  // epilogue: C row = m0+wm+i*16+l4*4+r, col = n0+wn+j*16+l15
#pragma unroll
  for (int i = 0; i < 4; i++) {
#pragma unroll
    for (int j = 0; j < 4; j++) {
      const long mb = m0 + wm + i * 16 + l4 * 4;
      const long n = n0 + wn + j * 16 + l15;
      if (EPI == 0) {
        short* C = (short*)Cv;
#pragma unroll
        for (int r = 0; r < 4; r++) {
          long m = mb + r;
          long idx = (((m >> 11) * 16 + (n >> 6)) * 2048 + (m & 2047)) * 64 + (n & 63);
          C[idx] = f2bs(acc[i][j][r] * scale);
        }
      } else if (EPI == 1) {
        short* C = (short*)Cv;
        long bb = mb >> 11, s = mb & 2047;
        long idx = ((bb * 16 + (n >> 6)) * 64 + (n & 63)) * 2048 + s;
        bf16x4 pk;
#pragma unroll
        for (int r = 0; r < 4; r++) pk[r] = f2bs(acc[i][j][r]);
        *(bf16x4*)(C + idx) = pk;
      } else if (EPI == 2) {
        float* C = (float*)Cv;
#pragma unroll
        for (int r = 0; r < 4; r++) {
          long m = mb + r;
          C[m * N + n] = acc[i][j][r] + X1[m * N + n];
        }
      } else if (EPI == 3) {
        short* C = (short*)Cv;
        float bb = X1[n];
#pragma unroll
        for (int r = 0; r < 4; r++) {
          float t = acc[i][j][r] + bb;
          C[(mb + r) * N + n] = f2bs(0.5f * t * (1.f + erff(t * 0.70710678118654752f)));
        }
      } else {
        float* C = (float*)Cv;
        float bb = X1[n];
#pragma unroll
        for (int r = 0; r < 4; r++) {
          long m = mb + r;
          C[m * N + n] = acc[i][j][r] + bb + X2[m * N + n];
        }
      }
    }
  }
}

// ---------------- flash attention (bf16 in/out, fp32 softmax) ---------------
// grid = (B*H)*16 ; 4 waves * 32 q-rows = 128 q-rows per block.
// Swapped QK^T: S^T = mfma(K, Q) so softmax over t is per-lane (16 vals) +
// shfl_xor(16,32).  P bounced through LDS [s][t] (stride 72, 16B-aligned
// b128 reads).  PV: O^T = mfma(V^T, P^T) with V pre-transposed [B,H,DV,S].
__global__ __launch_bounds__(256, 2) void k_attn(
    const short* __restrict__ Q, const short* __restrict__ Km, const short* __restrict__ Vt,
    const unsigned long long* __restrict__ Mb, short* __restrict__ O) {
  __shared__ short Pl[4][32][72];
  const int tid = threadIdx.x;
  const int wid = tid >> 6, lane = tid & 63;
  const int l15 = lane & 15, l4 = lane >> 4;
  const int bh = blockIdx.x >> 4;
  const int stile = blockIdx.x & 15;
  const int b = bh >> 4, hh = bh & 15;
  const int s0 = stile * 128 + wid * 32;
  const short* qb = Q + (long)bh * 2048 * 64;
  const short* kb = Km + (long)bh * 2048 * 64;
  const short* vb = Vt + (long)bh * 64 * 2048;
  const unsigned long long* mb = Mb + (long)b * 32 * 2048;

  bf16x8 qf[2][2];
#pragma unroll
  for (int fs = 0; fs < 2; fs++)
#pragma unroll
    for (int kt = 0; kt < 2; kt++)
      qf[fs][kt] = *(const bf16x8*)(qb + (long)(s0 + fs * 16 + l15) * 64 + kt * 32 + l4 * 8);

  float mrun[2] = {-INFINITY, -INFINITY};
  float lrun[2] = {0.f, 0.f};
  f32x4 oacc[4][2] = {};

  for (int tb = 0; tb < 32; tb++) {
    f32x4 sc[4][2] = {};
#pragma unroll
    for (int tf = 0; tf < 4; tf++)
#pragma unroll
      for (int kt = 0; kt < 2; kt++) {
        bf16x8 kf = *(const bf16x8*)(kb + (long)(tb * 64 + tf * 16 + l15) * 64 + kt * 32 + l4 * 8);
        sc[tf][0] = __builtin_amdgcn_mfma_f32_16x16x32_bf16(kf, qf[0][kt], sc[tf][0], 0, 0, 0);
        sc[tf][1] = __builtin_amdgcn_mfma_f32_16x16x32_bf16(kf, qf[1][kt], sc[tf][1], 0, 0, 0);
      }

#pragma unroll
    for (int fs = 0; fs < 2; fs++) {
      unsigned long long mw = mb[(long)tb * 2048 + s0 + fs * 16 + l15];
      float mx = -INFINITY;
#pragma unroll
      for (int tf = 0; tf < 4; tf++)
#pragma unroll
        for (int r = 0; r < 4; r++) {
          int t = tf * 16 + l4 * 4 + r;
          float sv = ((mw >> t) & 1ULL) ? sc[tf][fs][r] : -1e10f;
          sc[tf][fs][r] = sv;
          mx = fmaxf(mx, sv);
        }
      mx = fmaxf(mx, __shfl_xor(mx, 16));
      mx = fmaxf(mx, __shfl_xor(mx, 32));
      float mn = fmaxf(mrun[fs], mx);
      float fac = __expf(mrun[fs] - mn);  // first iter: exp(-inf)=0
      mrun[fs] = mn;
      float rsum = 0.f;
#pragma unroll
      for (int tf = 0; tf < 4; tf++)
#pragma unroll
        for (int r = 0; r < 4; r++) {
          float p = __expf(sc[tf][fs][r] - mn);
          sc[tf][fs][r] = p;
          rsum += p;
        }
      rsum += __shfl_xor(rsum, 16);
      rsum += __shfl_xor(rsum, 32);
      lrun[fs] = lrun[fs] * fac + rsum;
#pragma unroll
      for (int fdv = 0; fdv < 4; fdv++)
#pragma unroll
        for (int r = 0; r < 4; r++) oacc[fdv][fs][r] *= fac;
#pragma unroll
      for (int tf = 0; tf < 4; tf++) {
        bf16x4 pk;
#pragma unroll
        for (int r = 0; r < 4; r++) pk[r] = f2bs(sc[tf][fs][r]);
        *(bf16x4*)&Pl[wid][fs * 16 + l15][tf * 16 + l4 * 4] = pk;
      }
    }

    bf16x8 pf[2][2];
#pragma unroll
    for (int fs = 0; fs < 2; fs++)
#pragma unroll
      for (int kt = 0; kt < 2; kt++)
        pf[fs][kt] = *(const bf16x8*)&Pl[wid][fs * 16 + l15][kt * 32 + l4 * 8];

#pragma unroll
    for (int fdv = 0; fdv < 4; fdv++)
#pragma unroll
      for (int kt = 0; kt < 2; kt++) {
        bf16x8 vf = *(const bf16x8*)(vb + (long)(fdv * 16 + l15) * 2048 + tb * 64 + kt * 32 + l4 * 8);
        oacc[fdv][0] = __builtin_amdgcn_mfma_f32_16x16x32_bf16(vf, pf[0][kt], oacc[fdv][0], 0, 0, 0);
        oacc[fdv][1] = __builtin_amdgcn_mfma_f32_16x16x32_bf16(vf, pf[1][kt], oacc[fdv][1], 0, 0, 0);
      }
  }

  float li[2] = {1.f / lrun[0], 1.f / lrun[1]};
#pragma unroll
  for (int fdv = 0; fdv < 4; fdv++)
#pragma unroll
    for (int fs = 0; fs < 2; fs++) {
      bf16x4 ov;
#pragma unroll
      for (int r = 0; r < 4; r++) ov[r] = f2bs(oacc[fdv][fs][r] * li[fs]);
      int s = s0 + fs * 16 + l15;
      int dv = fdv * 16 + l4 * 4;
      *(bf16x4*)(O + ((long)b * 2048 + s) * 1024 + hh * 64 + dv) = ov;
    }
}

// ---------------------------------------------------------------------------
extern "C" void kernel_launch(void* const* d_in, const int* in_sizes, int n_in,
                              void* d_out, int out_size, void* d_ws, size_t ws_size,
                              hipStream_t stream) {
  const float* x   = (const float*)d_in[0];
  const int*   mask= (const int*)  d_in[1];
  const float* Wq  = (const float*)d_in[2];
  const float* Wk  = (const float*)d_in[3];
  const float* Wv  = (const float*)d_in[4];
  const float* Wo  = (const float*)d_in[5];
  const float* lag = (const float*)d_in[6];
  const float* lab = (const float*)d_in[7];
  const float* lfg = (const float*)d_in[8];
  const float* lfb = (const float*)d_in[9];
  const float* ffg = (const float*)d_in[10];
  const float* ffb = (const float*)d_in[11];
  const float* W1  = (const float*)d_in[12];
  const float* b1  = (const float*)d_in[13];
  const float* W2  = (const float*)d_in[14];
  const float* b2  = (const float*)d_in[15];
  float* out = (float*)d_out;

  const long MiB = 1048576L;
  char* w = (char*)d_ws;
  // ~154 MiB total; u overlaps dead q/k/vt, o overlaps dead h.
  short* h    = (short*)(w + 0);         // 16 MiB bf16 (LN1 out; reused as o)
  short* o    = h;
  short* q    = (short*)(w + 16 * MiB);  // 16 MiB bf16
  short* kbuf = (short*)(w + 32 * MiB);  // 16 MiB bf16
  short* vt   = (short*)(w + 48 * MiB);  // 16 MiB bf16
  short* u    = q;                       // 64 MiB bf16 (16..80; q/k/vt dead)
  float* attn = (float*)(w + 80 * MiB);  // 32 MiB fp32
  short* h2   = (short*)(w + 112 * MiB); // 16 MiB bf16
  short* wqt  = (short*)(w + 128 * MiB); // 2 MiB each (bf16)
  short* wkt  = wqt + 1048576;
  short* wvt  = wkt + 1048576;
  short* wot  = wvt + 1048576;
  short* w1t  = wot + 1048576;           // 8 MiB
  short* w2t  = w1t + 4194304;           // 8 MiB
  unsigned long long* mbt = (unsigned long long*)(w2t + 4194304);  // 2 MiB

  // weight transposes -> bf16 [N][K]
  k_transpose<<<dim3(2, 32, 16), 256, 0, stream>>>(Wq, wqt, 1024, 64);
  k_transpose<<<dim3(2, 32, 16), 256, 0, stream>>>(Wk, wkt, 1024, 64);
  k_transpose<<<dim3(2, 32, 16), 256, 0, stream>>>(Wv, wvt, 1024, 64);
  k_transpose<<<dim3(32, 32, 1), 256, 0, stream>>>(Wo, wot, 1024, 1024);
  k_transpose<<<dim3(128, 32, 1), 256, 0, stream>>>(W1, w1t, 1024, 4096);
  k_transpose<<<dim3(32, 128, 1), 256, 0, stream>>>(W2, w2t, 4096, 1024);
  k_packmask<<<65536, 256, 0, stream>>>(mask, mbt);

  k_ln<<<8192, 256, 0, stream>>>(x, lag, lab, h);

  k_gemm<0><<<512, 256, 0, stream>>>(h, wqt, q,    nullptr, nullptr, 8192, 1024, 1024, 0.125f);
  k_gemm<0><<<512, 256, 0, stream>>>(h, wkt, kbuf, nullptr, nullptr, 8192, 1024, 1024, 1.f);
  k_gemm<1><<<512, 256, 0, stream>>>(h, wvt, vt,   nullptr, nullptr, 8192, 1024, 1024, 1.f);

  k_attn<<<1024, 256, 0, stream>>>(q, kbuf, vt, mbt, o);

  k_gemm<2><<<512, 256, 0, stream>>>(o, wot, attn, x, nullptr, 8192, 1024, 1024, 1.f);

  k_ln2<<<8192, 256, 0, stream>>>(attn, lfg, lfb, ffg, ffb, h2);

  k_gemm<3><<<2048, 256, 0, stream>>>(h2, w1t, u, b1, nullptr, 8192, 4096, 1024, 1.f);
  k_gemm<4><<<512, 256, 0, stream>>>(u, w2t, out, b2, attn, 8192, 1024, 4096, 1.f);
}

// Round 3
// 543.313 us; speedup vs baseline: 1.2975x; 1.2975x over previous
//
#include <hip/hip_runtime.h>
#include <hip/hip_bf16.h>
#include <math.h>

// B=4 S=2048 D=1024 H=16 DK=DV=64 DI=4096.
// I/O: float tensors fp32 (per reference), mask int32, output fp32.
// Internal: bf16 MFMA operands, fp32 accumulation; `attn` residual fp32.

typedef __attribute__((ext_vector_type(8))) short bf16x8;  // 8 bf16 = 4 VGPR
typedef __attribute__((ext_vector_type(4))) short bf16x4;
typedef __attribute__((ext_vector_type(4))) float f32x4;

__device__ __forceinline__ float bs2f(short s) {
  union { unsigned u; float f; } c; c.u = ((unsigned)(unsigned short)s) << 16; return c.f;
}
__device__ __forceinline__ short f2bs(float x) {
  union { float f; unsigned u; } c; c.f = x;
  unsigned r = c.u + 0x7FFFu + ((c.u >> 16) & 1u);   // RNE
  return (short)(r >> 16);
}
__device__ __forceinline__ unsigned cvtpk(float lo, float hi) {
  unsigned r;
  asm("v_cvt_pk_bf16_f32 %0, %1, %2" : "=v"(r) : "v"(lo), "v"(hi));
  return r;
}

#if __has_builtin(__builtin_amdgcn_mfma_f32_16x16x16bf16_1k)
#define MFMA16(a, b, c) __builtin_amdgcn_mfma_f32_16x16x16bf16_1k(a, b, c, 0, 0, 0)
#elif __has_builtin(__builtin_amdgcn_mfma_f32_16x16x16_bf16)
#define MFMA16(a, b, c) __builtin_amdgcn_mfma_f32_16x16x16_bf16(a, b, c, 0, 0, 0)
#else
__device__ __forceinline__ f32x4 mfma16_asm(bf16x4 a, bf16x4 b, f32x4 c) {
  asm("v_mfma_f32_16x16x16_bf16 %0, %1, %2, %0" : "+v"(c) : "v"(a), "v"(b));
  return c;
}
#define MFMA16(a, b, c) mfma16_asm(a, b, c)
#endif

// ------ transpose+convert: in[R][C] fp32 -> out[C][R] bf16, batched ---------
__global__ __launch_bounds__(256) void k_transpose(const float* __restrict__ in,
                                                   short* __restrict__ out, int R, int C) {
  __shared__ float t[32][33];
  const long bat = blockIdx.z;
  const float* ib = in + bat * (long)R * C;
  short* ob = out + bat * (long)R * C;
  int tx = threadIdx.x & 31, ty = threadIdx.x >> 5;
  int r0 = blockIdx.y * 32, c0 = blockIdx.x * 32;
#pragma unroll
  for (int i = 0; i < 32; i += 8) t[ty + i][tx] = ib[(long)(r0 + ty + i) * C + c0 + tx];
  __syncthreads();
#pragma unroll
  for (int i = 0; i < 32; i += 8) ob[(long)(c0 + ty + i) * R + r0 + tx] = f2bs(t[tx][ty + i]);
}

// -------- mask pack: mask[b][s][t] int32 -> bits mbt[b][t/64][s] (u64) ------
__global__ __launch_bounds__(256) void k_packmask(const int* __restrict__ mask,
                                                  unsigned long long* __restrict__ mbt) {
  long gw = (long)blockIdx.x * 4 + (threadIdx.x >> 6);  // (b*2048+s)*32 + w
  int lane = threadIdx.x & 63;
  long bs = gw >> 5; int w = (int)(gw & 31);
  int b = (int)(bs >> 11), s = (int)(bs & 2047);
  int mval = mask[bs * 2048 + w * 64 + lane];
  unsigned long long bits = __ballot(mval != 0);
  if (lane == 0) mbt[((long)b * 32 + w) * 2048 + s] = bits;
}

// ------------- layernorm: X fp32 row(1024) -> Y bf16 ------------------------
__global__ __launch_bounds__(256) void k_ln(const float* __restrict__ X,
    const float* __restrict__ G, const float* __restrict__ Bb, short* __restrict__ Y) {
  __shared__ float ps[8];
  long row = blockIdx.x;
  int tid = threadIdx.x, wid = tid >> 6;
  f32x4 f = *(const f32x4*)(X + row * 1024 + tid * 4);
  float s = f[0] + f[1] + f[2] + f[3];
  float qq = f[0]*f[0] + f[1]*f[1] + f[2]*f[2] + f[3]*f[3];
#pragma unroll
  for (int o = 32; o; o >>= 1) { s += __shfl_xor(s, o); qq += __shfl_xor(qq, o); }
  if ((tid & 63) == 0) { ps[wid] = s; ps[4 + wid] = qq; }
  __syncthreads();
  s = ps[0] + ps[1] + ps[2] + ps[3];
  qq = ps[4] + ps[5] + ps[6] + ps[7];
  float mu = s * (1.f / 1024.f);
  float rstd = rsqrtf(qq * (1.f / 1024.f) - mu * mu + 1e-5f);
  f32x4 gv = *(const f32x4*)(G + tid * 4);
  f32x4 bv = *(const f32x4*)(Bb + tid * 4);
  bf16x4 yv;
#pragma unroll
  for (int i = 0; i < 4; i++) yv[i] = f2bs((f[i] - mu) * rstd * gv[i] + bv[i]);
  *(bf16x4*)(Y + row * 1024 + tid * 4) = yv;
}

// ------- double layernorm: X fp32 -> LN(LN(x;g1,b1);g2,b2) -> Y bf16 --------
__global__ __launch_bounds__(256) void k_ln2(const float* __restrict__ X,
    const float* __restrict__ G1, const float* __restrict__ B1,
    const float* __restrict__ G2, const float* __restrict__ B2, short* __restrict__ Y) {
  __shared__ float ps[8];
  long row = blockIdx.x;
  int tid = threadIdx.x, wid = tid >> 6;
  f32x4 f = *(const f32x4*)(X + row * 1024 + tid * 4);
  float s = f[0] + f[1] + f[2] + f[3];
  float qq = f[0]*f[0] + f[1]*f[1] + f[2]*f[2] + f[3]*f[3];
#pragma unroll
  for (int o = 32; o; o >>= 1) { s += __shfl_xor(s, o); qq += __shfl_xor(qq, o); }
  if ((tid & 63) == 0) { ps[wid] = s; ps[4 + wid] = qq; }
  __syncthreads();
  s = ps[0] + ps[1] + ps[2] + ps[3];
  qq = ps[4] + ps[5] + ps[6] + ps[7];
  float mu = s * (1.f / 1024.f);
  float rstd = rsqrtf(qq * (1.f / 1024.f) - mu * mu + 1e-5f);
  f32x4 g1 = *(const f32x4*)(G1 + tid * 4);
  f32x4 b1 = *(const f32x4*)(B1 + tid * 4);
  float y[4];
#pragma unroll
  for (int i = 0; i < 4; i++) y[i] = (f[i] - mu) * rstd * g1[i] + b1[i];
  __syncthreads();  // everyone done reading ps
  float s2 = y[0] + y[1] + y[2] + y[3];
  float q2 = y[0]*y[0] + y[1]*y[1] + y[2]*y[2] + y[3]*y[3];
#pragma unroll
  for (int o = 32; o; o >>= 1) { s2 += __shfl_xor(s2, o); q2 += __shfl_xor(q2, o); }
  if ((tid & 63) == 0) { ps[wid] = s2; ps[4 + wid] = q2; }
  __syncthreads();
  s2 = ps[0] + ps[1] + ps[2] + ps[3];
  q2 = ps[4] + ps[5] + ps[6] + ps[7];
  float mu2 = s2 * (1.f / 1024.f);
  float rstd2 = rsqrtf(q2 * (1.f / 1024.f) - mu2 * mu2 + 1e-5f);
  f32x4 g2 = *(const f32x4*)(G2 + tid * 4);
  f32x4 b2 = *(const f32x4*)(B2 + tid * 4);
  bf16x4 yv;
#pragma unroll
  for (int i = 0; i < 4; i++) yv[i] = f2bs((y[i] - mu2) * rstd2 * g2[i] + b2[i]);
  *(bf16x4*)(Y + row * 1024 + tid * 4) = yv;
}

// ---------------- GEMM: C[M,N] = A[M,K] * Bt[N,K]^T, bf16 operands ----------
// EPI: 0 = scale+store bf16 [B,H,S,DK] (q/k)   1 = store bf16 V^T [B,H,DV,S]
//      2 = +X1(fp32) residual -> fp32 row-major
//      3 = +bias X1(fp32), gelu -> bf16 row-major
//      4 = +bias X1(fp32) + X2(fp32) residual -> fp32 row-major
template<int EPI>
__global__ __launch_bounds__(256, 2) void k_gemm(
    const short* __restrict__ A, const short* __restrict__ Bt, void* __restrict__ Cv,
    const float* __restrict__ X1, const float* __restrict__ X2,
    int M, int N, int K, float scale) {
  __shared__ short As[128 * 32];
  __shared__ short Bs[128 * 32];
  const int tid = threadIdx.x;
  const int wid = tid >> 6, lane = tid & 63;
  const int ntn = N >> 7;
  const int tm = blockIdx.x / ntn, tn = blockIdx.x % ntn;
  const long m0 = (long)tm << 7, n0 = (long)tn << 7;
  const int wm = (wid >> 1) << 6, wn = (wid & 1) << 6;
  const int l15 = lane & 15, l4 = lane >> 4;

  f32x4 acc[4][4] = {};

  const short* Ag = A + (m0 + (tid >> 2)) * (long)K + (tid & 3) * 8;
  const short* Bg = Bt + (n0 + (tid >> 2)) * (long)K + (tid & 3) * 8;

  for (int kk = 0; kk < K; kk += 32) {
#pragma unroll
    for (int i = 0; i < 2; i++) {
      __builtin_amdgcn_global_load_lds(
          (const __attribute__((address_space(1))) unsigned int*)(Ag + kk + (long)i * 64 * K),
          (__attribute__((address_space(3))) unsigned int*)((char*)As + wid * 1024 + i * 4096),
          16, 0, 0);
      __builtin_amdgcn_global_load_lds(
          (const __attribute__((address_space(1))) unsigned int*)(Bg + kk + (long)i * 64 * K),
          (__attribute__((address_space(3))) unsigned int*)((char*)Bs + wid * 1024 + i * 4096),
          16, 0, 0);
    }
    __syncthreads();
    const int kof = l4 * 8;
    bf16x8 a[4], bfr[4];
#pragma unroll
    for (int i = 0; i < 4; i++) a[i] = *(const bf16x8*)(As + (wm + i * 16 + l15) * 32 + kof);
#pragma unroll
    for (int j = 0; j < 4; j++) bfr[j] = *(const bf16x8*)(Bs + (wn + j * 16 + l15) * 32 + kof);
#pragma unroll
    for (int i = 0; i < 4; i++)
#pragma unroll
      for (int j = 0; j < 4; j++)
        acc[i][j] = __builtin_amdgcn_mfma_f32_16x16x32_bf16(a[i], bfr[j], acc[i][j], 0, 0, 0);
    __syncthreads();
  }

  // epilogue: C row = m0+wm+i*16+l4*4+r, col = n0+wn+j*16+l15
#pragma unroll
  for (int i = 0; i < 4; i++) {
#pragma unroll
    for (int j = 0; j < 4; j++) {
      const long mb = m0 + wm + i * 16 + l4 * 4;
      const long n = n0 + wn + j * 16 + l15;
      if (EPI == 0) {
        short* C = (short*)Cv;
#pragma unroll
        for (int r = 0; r < 4; r++) {
          long m = mb + r;
          long idx = (((m >> 11) * 16 + (n >> 6)) * 2048 + (m & 2047)) * 64 + (n & 63);
          C[idx] = f2bs(acc[i][j][r] * scale);
        }
      } else if (EPI == 1) {
        short* C = (short*)Cv;
        long bb = mb >> 11, s = mb & 2047;
        long idx = ((bb * 16 + (n >> 6)) * 64 + (n & 63)) * 2048 + s;
        bf16x4 pk;
#pragma unroll
        for (int r = 0; r < 4; r++) pk[r] = f2bs(acc[i][j][r]);
        *(bf16x4*)(C + idx) = pk;
      } else if (EPI == 2) {
        float* C = (float*)Cv;
#pragma unroll
        for (int r = 0; r < 4; r++) {
          long m = mb + r;
          C[m * N + n] = acc[i][j][r] + X1[m * N + n];
        }
      } else if (EPI == 3) {
        short* C = (short*)Cv;
        float bb = X1[n];
#pragma unroll
        for (int r = 0; r < 4; r++) {
          float t = acc[i][j][r] + bb;
          C[(mb + r) * N + n] = f2bs(0.5f * t * (1.f + erff(t * 0.70710678118654752f)));
        }
      } else {
        float* C = (float*)Cv;
        float bb = X1[n];
#pragma unroll
        for (int r = 0; r < 4; r++) {
          long m = mb + r;
          C[m * N + n] = acc[i][j][r] + bb + X2[m * N + n];
        }
      }
    }
  }
}

// ---------------- flash attention, LDS-staged K/V, register P ----------------
// grid = (B*H)*16 ; 4 waves * 32 q-rows = 128 q-rows per block.
// Swapped QK^T: S^T = mfma_16x16x32(K, Q) so softmax over t is per-lane (16
// vals) + shfl_xor(16,32).  PV uses mfma_16x16x16 whose k-distribution
// (l4*4+j) EXACTLY matches the QK output layout (t = tf*16+l4*4+r) -> P stays
// in registers (cvt_pk_bf16_f32 pairs), no LDS bounce.
// K/V tiles (64x64 bf16 = 8KB each) staged via global_load_lds, double
// buffered, 16B-slot XOR swizzle (pre-swizzled source, swizzled ds_read).
__global__ __launch_bounds__(256, 4) void k_attn(
    const short* __restrict__ Q, const short* __restrict__ Km, const short* __restrict__ Vt,
    const unsigned long long* __restrict__ Mb, short* __restrict__ O) {
  __shared__ char KV[2][16384];  // per dbuf: [0,8K)=K tile, [8K,16K)=V tile
  const int tid = threadIdx.x;
  const int wid = tid >> 6, lane = tid & 63;
  const int l15 = lane & 15, l4 = lane >> 4;
  const int p4 = (l15 & 7) << 4;          // read-side 16B-slot XOR
  const int bh = blockIdx.x >> 4;
  const int stile = blockIdx.x & 15;
  const int b = bh >> 4, hh = bh & 15;
  const int s0 = stile * 128 + wid * 32;
  const short* qb = Q + (long)bh * 2048 * 64;
  const short* kb = Km + (long)bh * 2048 * 64;
  const short* vb = Vt + (long)bh * 64 * 2048;
  const unsigned long long* mb = Mb + (long)b * 32 * 2048;
  char* lds = (char*)KV;

  // staging addressing: 256 thr x 16B = 4KB = 32 rows per issue, 2 issues/tile
  const int srow = tid >> 3;
  const int sl8 = (((tid & 7) ^ (srow & 7)) << 3);  // pre-swizzled col (elems)

  auto STAGE = [&](int db, int tbn) {
#pragma unroll
    for (int i = 0; i < 2; i++) {
      const int row = i * 32 + srow;
      const short* ks = kb + ((long)tbn * 64 + row) * 64 + sl8;
      const short* vs = vb + (long)row * 2048 + tbn * 64 + sl8;
      __builtin_amdgcn_global_load_lds(
          (const __attribute__((address_space(1))) unsigned int*)ks,
          (__attribute__((address_space(3))) unsigned int*)(lds + db * 16384 + i * 4096 + wid * 1024),
          16, 0, 0);
      __builtin_amdgcn_global_load_lds(
          (const __attribute__((address_space(1))) unsigned int*)vs,
          (__attribute__((address_space(3))) unsigned int*)(lds + db * 16384 + 8192 + i * 4096 + wid * 1024),
          16, 0, 0);
    }
  };

  bf16x8 qf[2][2];
#pragma unroll
  for (int fs = 0; fs < 2; fs++)
#pragma unroll
    for (int kt = 0; kt < 2; kt++)
      qf[fs][kt] = *(const bf16x8*)(qb + (long)(s0 + fs * 16 + l15) * 64 + kt * 32 + l4 * 8);

  float mrun[2] = {-INFINITY, -INFINITY};
  float lrun[2] = {0.f, 0.f};
  f32x4 oacc[4][2] = {};

  STAGE(0, 0);
  asm volatile("s_waitcnt vmcnt(0)" ::: "memory");
  __builtin_amdgcn_s_barrier();

  const float L2E = 1.44269504088896340736f;
  for (int tb = 0; tb < 32; tb++) {
    const int db = tb & 1;
    if (tb < 31) STAGE(db ^ 1, tb + 1);

    // ---- QK^T from staged K ----
    const char* Kl = lds + db * 16384;
    f32x4 sc[4][2] = {};
#pragma unroll
    for (int tf = 0; tf < 4; tf++) {
      const int t = tf * 16 + l15;
#pragma unroll
      for (int kt = 0; kt < 2; kt++) {
        bf16x8 kf = *(const bf16x8*)(Kl + t * 128 + ((kt * 64 + l4 * 16) ^ p4));
        sc[tf][0] = __builtin_amdgcn_mfma_f32_16x16x32_bf16(kf, qf[0][kt], sc[tf][0], 0, 0, 0);
        sc[tf][1] = __builtin_amdgcn_mfma_f32_16x16x32_bf16(kf, qf[1][kt], sc[tf][1], 0, 0, 0);
      }
    }

    // ---- online softmax (per-lane rows) + pack P to bf16 in registers ----
    unsigned pw[2][4][2];
#pragma unroll
    for (int fs = 0; fs < 2; fs++) {
      unsigned long long mw = mb[(long)tb * 2048 + s0 + fs * 16 + l15];
      float mx = mrun[fs];
#pragma unroll
      for (int tf = 0; tf < 4; tf++) {
        unsigned nib = ((unsigned)(mw >> (tf * 16 + l4 * 4))) & 15u;
#pragma unroll
        for (int r = 0; r < 4; r++)
          sc[tf][fs][r] = (nib & (1u << r)) ? sc[tf][fs][r] : -1e10f;
        mx = fmaxf(mx, fmaxf(fmaxf(sc[tf][fs][0], sc[tf][fs][1]),
                             fmaxf(sc[tf][fs][2], sc[tf][fs][3])));
      }
      mx = fmaxf(mx, __shfl_xor(mx, 16));
      mx = fmaxf(mx, __shfl_xor(mx, 32));
      if (!__all(mx <= mrun[fs] + 8.f)) {   // defer-max: rescale only on growth
        float fac = __expf(mrun[fs] - mx);
        mrun[fs] = mx;
        lrun[fs] *= fac;
#pragma unroll
        for (int fdv = 0; fdv < 4; fdv++)
#pragma unroll
          for (int r = 0; r < 4; r++) oacc[fdv][fs][r] *= fac;
      }
      const float cc = -mrun[fs] * L2E;
      float rsum = 0.f;
#pragma unroll
      for (int tf = 0; tf < 4; tf++) {
#pragma unroll
        for (int r = 0; r < 4; r++) {
          float p = exp2f(fmaf(sc[tf][fs][r], L2E, cc));
          sc[tf][fs][r] = p;
          rsum += p;
        }
        pw[fs][tf][0] = cvtpk(sc[tf][fs][0], sc[tf][fs][1]);
        pw[fs][tf][1] = cvtpk(sc[tf][fs][2], sc[tf][fs][3]);
      }
      rsum += __shfl_xor(rsum, 16);
      rsum += __shfl_xor(rsum, 32);
      lrun[fs] += rsum;
    }

    // ---- PV from staged V^T with 16x16x16 MFMA (P register-resident) ----
    const char* Vl = lds + db * 16384 + 8192;
#pragma unroll
    for (int fdv = 0; fdv < 4; fdv++) {
      const int dv = fdv * 16 + l15;
#pragma unroll
      for (int tf = 0; tf < 4; tf++) {
        bf16x4 vf = *(const bf16x4*)(Vl + dv * 128 + ((tf * 32 + l4 * 8) ^ p4));
        union { unsigned u[2]; bf16x4 v; } p0, p1;
        p0.u[0] = pw[0][tf][0]; p0.u[1] = pw[0][tf][1];
        p1.u[0] = pw[1][tf][0]; p1.u[1] = pw[1][tf][1];
        oacc[fdv][0] = MFMA16(vf, p0.v, oacc[fdv][0]);
        oacc[fdv][1] = MFMA16(vf, p1.v, oacc[fdv][1]);
      }
    }

    asm volatile("s_waitcnt vmcnt(0)" ::: "memory");  // next-tile stage landed
    __builtin_amdgcn_s_barrier();                     // all waves done with cur
  }

  float li[2] = {1.f / lrun[0], 1.f / lrun[1]};
#pragma unroll
  for (int fdv = 0; fdv < 4; fdv++)
#pragma unroll
    for (int fs = 0; fs < 2; fs++) {
      bf16x4 ov;
#pragma unroll
      for (int r = 0; r < 4; r++) ov[r] = f2bs(oacc[fdv][fs][r] * li[fs]);
      int s = s0 + fs * 16 + l15;
      int dv = fdv * 16 + l4 * 4;
      *(bf16x4*)(O + ((long)b * 2048 + s) * 1024 + hh * 64 + dv) = ov;
    }
}

// ---------------------------------------------------------------------------
extern "C" void kernel_launch(void* const* d_in, const int* in_sizes, int n_in,
                              void* d_out, int out_size, void* d_ws, size_t ws_size,
                              hipStream_t stream) {
  const float* x   = (const float*)d_in[0];
  const int*   mask= (const int*)  d_in[1];
  const float* Wq  = (const float*)d_in[2];
  const float* Wk  = (const float*)d_in[3];
  const float* Wv  = (const float*)d_in[4];
  const float* Wo  = (const float*)d_in[5];
  const float* lag = (const float*)d_in[6];
  const float* lab = (const float*)d_in[7];
  const float* lfg = (const float*)d_in[8];
  const float* lfb = (const float*)d_in[9];
  const float* ffg = (const float*)d_in[10];
  const float* ffb = (const float*)d_in[11];
  const float* W1  = (const float*)d_in[12];
  const float* b1  = (const float*)d_in[13];
  const float* W2  = (const float*)d_in[14];
  const float* b2  = (const float*)d_in[15];
  float* out = (float*)d_out;

  const long MiB = 1048576L;
  char* w = (char*)d_ws;
  short* h    = (short*)(w + 0);         // 16 MiB bf16 (LN1 out; reused as o)
  short* o    = h;
  short* q    = (short*)(w + 16 * MiB);  // 16 MiB bf16
  short* kbuf = (short*)(w + 32 * MiB);  // 16 MiB bf16
  short* vt   = (short*)(w + 48 * MiB);  // 16 MiB bf16
  short* u    = q;                       // 64 MiB bf16 (16..80; q/k/vt dead)
  float* attn = (float*)(w + 80 * MiB);  // 32 MiB fp32
  short* h2   = (short*)(w + 112 * MiB); // 16 MiB bf16
  short* wqt  = (short*)(w + 128 * MiB); // 2 MiB each (bf16)
  short* wkt  = wqt + 1048576;
  short* wvt  = wkt + 1048576;
  short* wot  = wvt + 1048576;
  short* w1t  = wot + 1048576;           // 8 MiB
  short* w2t  = w1t + 4194304;           // 8 MiB
  unsigned long long* mbt = (unsigned long long*)(w2t + 4194304);  // 2 MiB

  // weight transposes -> bf16 [N][K]
  k_transpose<<<dim3(2, 32, 16), 256, 0, stream>>>(Wq, wqt, 1024, 64);
  k_transpose<<<dim3(2, 32, 16), 256, 0, stream>>>(Wk, wkt, 1024, 64);
  k_transpose<<<dim3(2, 32, 16), 256, 0, stream>>>(Wv, wvt, 1024, 64);
  k_transpose<<<dim3(32, 32, 1), 256, 0, stream>>>(Wo, wot, 1024, 1024);
  k_transpose<<<dim3(128, 32, 1), 256, 0, stream>>>(W1, w1t, 1024, 4096);
  k_transpose<<<dim3(32, 128, 1), 256, 0, stream>>>(W2, w2t, 4096, 1024);
  k_packmask<<<65536, 256, 0, stream>>>(mask, mbt);

  k_ln<<<8192, 256, 0, stream>>>(x, lag, lab, h);

  k_gemm<0><<<512, 256, 0, stream>>>(h, wqt, q,    nullptr, nullptr, 8192, 1024, 1024, 0.125f);
  k_gemm<0><<<512, 256, 0, stream>>>(h, wkt, kbuf, nullptr, nullptr, 8192, 1024, 1024, 1.f);
  k_gemm<1><<<512, 256, 0, stream>>>(h, wvt, vt,   nullptr, nullptr, 8192, 1024, 1024, 1.f);

  k_attn<<<1024, 256, 0, stream>>>(q, kbuf, vt, mbt, o);

  k_gemm<2><<<512, 256, 0, stream>>>(o, wot, attn, x, nullptr, 8192, 1024, 1024, 1.f);

  k_ln2<<<8192, 256, 0, stream>>>(attn, lfg, lfb, ffg, ffb, h2);

  k_gemm<3><<<2048, 256, 0, stream>>>(h2, w1t, u, b1, nullptr, 8192, 4096, 1024, 1.f);
  k_gemm<4><<<512, 256, 0, stream>>>(u, w2t, out, b2, attn, 8192, 1024, 4096, 1.f);
}